// Round 2
// baseline (1298.561 us; speedup 1.0000x reference)
//
#include <hip/hip_runtime.h>

#define N_NODES 100000
#define N_EDGES 1600000
#define D 128
#define EPS 1e-5f

#define CHUNK 1024
#define NB_SCAN ((N_NODES + CHUNK - 1) / CHUNK)   // 98

// ---------------- CSR build ----------------

__global__ void k_hist(const int* __restrict__ ei, int* __restrict__ deg) {
    int e = blockIdx.x * blockDim.x + threadIdx.x;
    if (e < N_EDGES) {
        int d = ei[N_EDGES + e];   // dst row (int32!)
        atomicAdd(&deg[d], 1);
    }
}

__global__ void k_scan1(const int* __restrict__ deg, int* __restrict__ bsum) {
    __shared__ int s[256];
    int b = blockIdx.x, t = threadIdx.x;
    int base = b * CHUNK + t * 4;
    int sum = 0;
#pragma unroll
    for (int j = 0; j < 4; ++j) {
        int i = base + j;
        if (i < N_NODES) sum += deg[i];
    }
    s[t] = sum;
    __syncthreads();
    for (int off = 128; off > 0; off >>= 1) {
        if (t < off) s[t] += s[t + off];
        __syncthreads();
    }
    if (t == 0) bsum[b] = s[0];
}

__global__ void k_scan2(int* __restrict__ bsum, int* __restrict__ row_start) {
    // single thread: exclusive scan over NB_SCAN block sums
    int run = 0;
    for (int b = 0; b < NB_SCAN; ++b) {
        int v = bsum[b];
        bsum[b] = run;
        run += v;
    }
    row_start[N_NODES] = run;   // == N_EDGES
}

__global__ void k_scan3(const int* __restrict__ deg, const int* __restrict__ bsum,
                        int* __restrict__ row_start, int* __restrict__ cursor) {
    __shared__ int s[256];
    int b = blockIdx.x, t = threadIdx.x;
    int base = b * CHUNK + t * 4;
    int v[4];
    int sum = 0;
#pragma unroll
    for (int j = 0; j < 4; ++j) {
        int i = base + j;
        v[j] = (i < N_NODES) ? deg[i] : 0;
        sum += v[j];
    }
    s[t] = sum;
    __syncthreads();
    // inclusive Hillis-Steele scan over 256 thread sums
    for (int off = 1; off < 256; off <<= 1) {
        int x = (t >= off) ? s[t - off] : 0;
        __syncthreads();
        s[t] += x;
        __syncthreads();
    }
    int excl = s[t] - sum + bsum[b];
#pragma unroll
    for (int j = 0; j < 4; ++j) {
        int i = base + j;
        if (i < N_NODES) { row_start[i] = excl; cursor[i] = excl; }
        excl += v[j];
    }
}

__global__ void k_fill(const int* __restrict__ ei, int* __restrict__ cursor,
                       int* __restrict__ csr_src) {
    int e = blockIdx.x * blockDim.x + threadIdx.x;
    if (e < N_EDGES) {
        int s = ei[e];              // src row
        int d = ei[N_EDGES + e];    // dst row
        int pos = atomicAdd(&cursor[d], 1);
        csr_src[pos] = s;
    }
}

// ---------------- fused dual GEMM: Z = X@Wl^T, Y = X@Wr^T + b ----------------
// X tile (64 rows x 128) staged in LDS once, shared by both GEMMs.
// Y may alias X: each block reads only its own 64 rows (into LDS, before
// __syncthreads) and writes only those rows at the end.
template <int DOUT>
__global__ __launch_bounds__(256) void k_gemm2(
    const float* __restrict__ X,
    const float* __restrict__ Wl, const float* __restrict__ Wr,
    const float* __restrict__ bias,
    float* __restrict__ Z, float* __restrict__ Y) {
    constexpr int TN = 64;
    constexpr int OGC = DOUT / 4;    // output groups (4 outputs each): 32 or 16
    constexpr int NGC = 256 / OGC;   // node groups: 8 or 16
    constexpr int NPT = TN / NGC;    // nodes per thread: 8 or 4

    __shared__ float sX[TN][D];

    int t = threadIdx.x;
    int n0 = blockIdx.x * TN;

    // stage X tile: 64*32 = 2048 float4, 8 iters of 256 threads
#pragma unroll
    for (int r = 0; r < 8; ++r) {
        int idx = t + r * 256;
        int row = idx >> 5;            // 32 float4 per row
        int c4 = (idx & 31) * 4;
        int rr = n0 + row;
        if (rr >= N_NODES) rr = N_NODES - 1;
        *(float4*)&sX[row][c4] = *(const float4*)&X[(size_t)rr * D + c4];
    }
    __syncthreads();

    int og = t % OGC, ng = t / OGC;
    int o0 = og * 4;
    int nb = ng * NPT;

    float accZ[NPT][4], accY[NPT][4];
#pragma unroll
    for (int nn = 0; nn < NPT; ++nn)
#pragma unroll
        for (int j = 0; j < 4; ++j) { accZ[nn][j] = 0.f; accY[nn][j] = 0.f; }

    for (int i = 0; i < D; i += 4) {
        float4 wl[4], wr[4];
#pragma unroll
        for (int j = 0; j < 4; ++j) {
            wl[j] = *(const float4*)&Wl[(size_t)(o0 + j) * D + i];
            wr[j] = *(const float4*)&Wr[(size_t)(o0 + j) * D + i];
        }
#pragma unroll
        for (int nn = 0; nn < NPT; ++nn) {
            float4 a = *(const float4*)&sX[nb + nn][i];
#pragma unroll
            for (int j = 0; j < 4; ++j) {
                accZ[nn][j] += a.x * wl[j].x + a.y * wl[j].y + a.z * wl[j].z + a.w * wl[j].w;
                accY[nn][j] += a.x * wr[j].x + a.y * wr[j].y + a.z * wr[j].z + a.w * wr[j].w;
            }
        }
    }

    float4 bv = *(const float4*)&bias[o0];
    const float* pb = (const float*)&bv;
#pragma unroll
    for (int nn = 0; nn < NPT; ++nn) {
        int n = n0 + nb + nn;
        if (n < N_NODES) {
            float4 oz, oy;
            float* pz = (float*)&oz;
            float* py = (float*)&oy;
#pragma unroll
            for (int j = 0; j < 4; ++j) {
                pz[j] = accZ[nn][j];
                py[j] = accY[nn][j] + pb[j];
            }
            *(float4*)&Z[(size_t)n * DOUT + o0] = oz;
            *(float4*)&Y[(size_t)n * DOUT + o0] = oy;
        }
    }
}

// ---------------- mean aggregation + epilogue ----------------
// H[n][c] = Y[n][c] + mean_e Z[src(e)][c]; optional BN+ReLU. In-place on Y.
// one block (DOUT threads) per node; thread c owns channel c.
template <int DOUT, bool BNRELU>
__global__ void k_agg(const float* __restrict__ Z, const int* __restrict__ row_start,
                      const int* __restrict__ csr_src,
                      const float* __restrict__ gamma, const float* __restrict__ beta,
                      const float* __restrict__ mean, const float* __restrict__ var,
                      float* __restrict__ HY) {
    int n = blockIdx.x;
    int c = threadIdx.x;
    int s0 = row_start[n], s1 = row_start[n + 1];
    float acc = 0.f;
    for (int e = s0; e < s1; ++e) {
        int s = csr_src[e];
        acc += Z[(size_t)s * DOUT + c];
    }
    float dg = (float)(s1 - s0);
    float h = HY[(size_t)n * DOUT + c] + acc / fmaxf(dg, 1.f);
    if (BNRELU) {
        h = (h - mean[c]) * (gamma[c] * rsqrtf(var[c] + EPS)) + beta[c];
        h = fmaxf(h, 0.f);
    }
    HY[(size_t)n * DOUT + c] = h;
}

// ---------------- launch ----------------

static inline size_t align256(size_t x) { return (x + 255) & ~(size_t)255; }

extern "C" void kernel_launch(void* const* d_in, const int* in_sizes, int n_in,
                              void* d_out, int out_size, void* d_ws, size_t ws_size,
                              hipStream_t stream) {
    const float* x    = (const float*)d_in[0];
    const int*   ei   = (const int*)d_in[1];      // int32! (JAX default int)
    const float* w_l1 = (const float*)d_in[2];
    const float* b_l1 = (const float*)d_in[3];
    const float* w_r1 = (const float*)d_in[4];
    const float* g1   = (const float*)d_in[5];
    const float* be1  = (const float*)d_in[6];
    const float* m1   = (const float*)d_in[7];
    const float* v1   = (const float*)d_in[8];
    const float* w_l2 = (const float*)d_in[9];
    const float* b_l2 = (const float*)d_in[10];
    const float* w_r2 = (const float*)d_in[11];
    const float* g2   = (const float*)d_in[12];
    const float* be2  = (const float*)d_in[13];
    const float* m2   = (const float*)d_in[14];
    const float* v2   = (const float*)d_in[15];
    const float* w_l3 = (const float*)d_in[16];
    const float* b_l3 = (const float*)d_in[17];
    const float* w_r3 = (const float*)d_in[18];
    float* out = (float*)d_out;

    char* w = (char*)d_ws;
    int* deg       = (int*)w;  w += align256((size_t)N_NODES * 4);
    int* row_start = (int*)w;  w += align256((size_t)(N_NODES + 1) * 4);
    int* cursor    = (int*)w;  w += align256((size_t)N_NODES * 4);
    int* bsum      = (int*)w;  w += align256((size_t)NB_SCAN * 4);
    int* csr_src   = (int*)w;  w += align256((size_t)N_EDGES * 4);
    float* bufA    = (float*)w; w += align256((size_t)N_NODES * D * 4);
    float* bufB    = (float*)w; w += align256((size_t)N_NODES * D * 4);

    hipMemsetAsync(deg, 0, (size_t)N_NODES * 4, stream);

    int eb = (N_EDGES + 255) / 256;
    k_hist<<<eb, 256, 0, stream>>>(ei, deg);
    k_scan1<<<NB_SCAN, 256, 0, stream>>>(deg, bsum);
    k_scan2<<<1, 1, 0, stream>>>(bsum, row_start);
    k_scan3<<<NB_SCAN, 256, 0, stream>>>(deg, bsum, row_start, cursor);
    k_fill<<<eb, 256, 0, stream>>>(ei, cursor, csr_src);

    int gb = (N_NODES + 63) / 64;   // 1563

    // layer 1: Z1 = x@Wl1^T -> bufB, Y1 = x@Wr1^T + b1 -> bufA; h1 = bufA
    k_gemm2<128><<<gb, 256, 0, stream>>>(x, w_l1, w_r1, b_l1, bufB, bufA);
    k_agg<128, true><<<N_NODES, 128, 0, stream>>>(bufB, row_start, csr_src, g1, be1, m1, v1, bufA);

    // layer 2: Z2 -> bufB, Y2 -> bufA (in-place over h1; safe: per-block row ownership)
    k_gemm2<128><<<gb, 256, 0, stream>>>(bufA, w_l2, w_r2, b_l2, bufB, bufA);
    k_agg<128, true><<<N_NODES, 128, 0, stream>>>(bufB, row_start, csr_src, g2, be2, m2, v2, bufA);

    // layer 3: Z3 -> bufB (N x 64), Y3 -> out; final H accumulated into out
    k_gemm2<64><<<gb, 256, 0, stream>>>(bufA, w_l3, w_r3, b_l3, bufB, out);
    k_agg<64, false><<<N_NODES, 64, 0, stream>>>(bufB, row_start, csr_src, b_l3, b_l3, b_l3, b_l3, out);
}

// Round 3
// 514.525 us; speedup vs baseline: 2.5238x; 2.5238x over previous
//
#include <hip/hip_runtime.h>

#define N_NODES 100000
#define N_EDGES 1600000
#define D 128
#define EPS 1e-5f

#define CHUNK 1024
#define NB_SCAN ((N_NODES + CHUNK - 1) / CHUNK)   // 98

typedef unsigned int uint;
typedef unsigned short ushort;
using bf16x8 = __attribute__((ext_vector_type(8))) short;
using f32x4  = __attribute__((ext_vector_type(4))) float;

__device__ __forceinline__ ushort f2bf(float f) {
    uint u = __float_as_uint(f);
    return (ushort)((u + 0x7fffu + ((u >> 16) & 1u)) >> 16);   // RNE
}

// ---------------- CSR build ----------------

__global__ void k_hist(const int* __restrict__ ei, int* __restrict__ deg) {
    int e = blockIdx.x * blockDim.x + threadIdx.x;
    if (e < N_EDGES) atomicAdd(&deg[ei[N_EDGES + e]], 1);
}

__global__ void k_scan1(const int* __restrict__ deg, int* __restrict__ bsum) {
    __shared__ int s[256];
    int b = blockIdx.x, t = threadIdx.x;
    int base = b * CHUNK + t * 4;
    int sum = 0;
#pragma unroll
    for (int j = 0; j < 4; ++j) {
        int i = base + j;
        if (i < N_NODES) sum += deg[i];
    }
    s[t] = sum;
    __syncthreads();
    for (int off = 128; off > 0; off >>= 1) {
        if (t < off) s[t] += s[t + off];
        __syncthreads();
    }
    if (t == 0) bsum[b] = s[0];
}

__global__ void k_scan2(int* __restrict__ bsum, int* __restrict__ row_start) {
    int run = 0;
    for (int b = 0; b < NB_SCAN; ++b) {
        int v = bsum[b];
        bsum[b] = run;
        run += v;
    }
    row_start[N_NODES] = run;
}

__global__ void k_scan3(const int* __restrict__ deg, const int* __restrict__ bsum,
                        int* __restrict__ row_start, int* __restrict__ cursor) {
    __shared__ int s[256];
    int b = blockIdx.x, t = threadIdx.x;
    int base = b * CHUNK + t * 4;
    int v[4];
    int sum = 0;
#pragma unroll
    for (int j = 0; j < 4; ++j) {
        int i = base + j;
        v[j] = (i < N_NODES) ? deg[i] : 0;
        sum += v[j];
    }
    s[t] = sum;
    __syncthreads();
    for (int off = 1; off < 256; off <<= 1) {
        int x = (t >= off) ? s[t - off] : 0;
        __syncthreads();
        s[t] += x;
        __syncthreads();
    }
    int excl = s[t] - sum + bsum[b];
#pragma unroll
    for (int j = 0; j < 4; ++j) {
        int i = base + j;
        if (i < N_NODES) { row_start[i] = excl; cursor[i] = excl; }
        excl += v[j];
    }
}

__global__ void k_fill(const int* __restrict__ ei, int* __restrict__ cursor,
                       int* __restrict__ csr_src) {
    int e = blockIdx.x * blockDim.x + threadIdx.x;
    if (e < N_EDGES) {
        int s = ei[e];
        int d = ei[N_EDGES + e];
        int pos = atomicAdd(&cursor[d], 1);
        csr_src[pos] = s;
    }
}

// ---------------- casts ----------------

__global__ void k_cast_x(const float* __restrict__ in, ushort* __restrict__ out, int n4) {
    int i = blockIdx.x * blockDim.x + threadIdx.x;
    if (i < n4) {
        float4 v = ((const float4*)in)[i];
        ushort4 o;
        o.x = f2bf(v.x); o.y = f2bf(v.y); o.z = f2bf(v.z); o.w = f2bf(v.w);
        ((ushort4*)out)[i] = o;
    }
}

__global__ void k_cast_w(const float* __restrict__ Wl, const float* __restrict__ Wr,
                         ushort* __restrict__ W2, int dout) {
    int i = blockIdx.x * blockDim.x + threadIdx.x;
    int total = 2 * dout * D;
    if (i < total) {
        int o = i >> 7, k = i & 127;
        float v = (o < dout) ? Wl[o * D + k] : Wr[(o - dout) * D + k];
        W2[i] = f2bf(v);
    }
}

// ---------------- MFMA dual GEMM ----------------
// Z = X@Wl^T (bf16 out), Y = X@Wr^T + b (f32 out). X: [N][128] bf16.
// W2: [2*DOUT][128] bf16 (Wl rows then Wr rows).
// Block: 256 thr (4 waves) x 64-row tile. Wave w owns rows 16w..16w+15,
// computes all 2*DOUT outputs. Weights staged fragment-ordered in LDS.
template <int DOUT>
__global__ __launch_bounds__(256) void k_gemm_mfma(
    const ushort* __restrict__ Xb, const ushort* __restrict__ W2,
    const float* __restrict__ bias,
    ushort* __restrict__ Zb, float* __restrict__ Yf) {
    constexpr int NT = 2 * DOUT;       // 256 or 128 outputs
    constexpr int OT = NT / 16;        // 16 or 8 otiles

    __shared__ ushort sW[OT * 4 * 64 * 8];   // 64 KB / 32 KB, fragment order

    int t = threadIdx.x;
    int n0 = blockIdx.x * 64;

    // A fragments first (overlap with staging): wave w, lane l
    int w = t >> 6, l = t & 63;
    int arow = n0 + 16 * w + (l & 15);
    if (arow >= N_NODES) arow = N_NODES - 1;
    const ushort* ap = &Xb[(size_t)arow * D + ((l >> 4) * 8)];
    bf16x8 afr[4];
#pragma unroll
    for (int kt = 0; kt < 4; ++kt) afr[kt] = *(const bf16x8*)(ap + kt * 32);

    // stage W fragments: slot s -> frag f = s>>6, lane = s&63
    // element: o = (f>>2)*16 + (lane&15), k = (f&3)*32 + (lane>>4)*8, 8 contiguous k
    for (int s = t; s < OT * 4 * 64; s += 256) {
        int f = s >> 6, ln = s & 63;
        int o = (f >> 2) * 16 + (ln & 15);
        int k = (f & 3) * 32 + ((ln >> 4) * 8);
        *(uint4*)&sW[s * 8] = *(const uint4*)&W2[o * D + k];
    }
    __syncthreads();

    f32x4 acc[OT];
#pragma unroll
    for (int ot = 0; ot < OT; ++ot) acc[ot] = (f32x4){0.f, 0.f, 0.f, 0.f};

#pragma unroll
    for (int kt = 0; kt < 4; ++kt) {
#pragma unroll
        for (int ot = 0; ot < OT; ++ot) {
            bf16x8 bfr = *(const bf16x8*)&sW[((ot * 4 + kt) * 64 + l) * 8];
            acc[ot] = __builtin_amdgcn_mfma_f32_16x16x32_bf16(afr[kt], bfr, acc[ot], 0, 0, 0);
        }
    }
    __syncthreads();

    // dump acc to LDS as f32 [64][NT]; C map: row=(l>>4)*4+j, col=l&15
    float* sC = (float*)sW;
    int r0 = (l >> 4) * 4;
#pragma unroll
    for (int ot = 0; ot < OT; ++ot)
#pragma unroll
        for (int j = 0; j < 4; ++j)
            sC[(16 * w + r0 + j) * NT + ot * 16 + (l & 15)] = acc[ot][j];
    __syncthreads();

    // Z: cols [0,DOUT) -> bf16, ushort8 chunks
    constexpr int ZC = DOUT / 8;       // chunks per row
    for (int c = t; c < 64 * ZC; c += 256) {
        int r = c / ZC, cc = (c % ZC) * 8;
        if (n0 + r < N_NODES) {
            uint4 pk;
            uint* pw = (uint*)&pk;
#pragma unroll
            for (int j = 0; j < 4; ++j) {
                float f0 = sC[r * NT + cc + 2 * j];
                float f1 = sC[r * NT + cc + 2 * j + 1];
                pw[j] = (uint)f2bf(f0) | ((uint)f2bf(f1) << 16);
            }
            *(uint4*)&Zb[(size_t)(n0 + r) * DOUT + cc] = pk;
        }
    }
    // Y: cols [DOUT,2*DOUT) + bias -> f32, float4 chunks
    constexpr int YC = DOUT / 4;
    for (int c = t; c < 64 * YC; c += 256) {
        int r = c / YC, cc = (c % YC) * 4;
        if (n0 + r < N_NODES) {
            float4 bv = *(const float4*)&bias[cc];
            float4 o;
            o.x = sC[r * NT + DOUT + cc + 0] + bv.x;
            o.y = sC[r * NT + DOUT + cc + 1] + bv.y;
            o.z = sC[r * NT + DOUT + cc + 2] + bv.z;
            o.w = sC[r * NT + DOUT + cc + 3] + bv.w;
            *(float4*)&Yf[(size_t)(n0 + r) * DOUT + cc] = o;
        }
    }
}

// ---------------- mean aggregation + epilogue ----------------
// H[n][c] = Y[n][c] + mean_e Z[src(e)][c]; optional BN+ReLU.
// 64 threads/block; NPB nodes/block; each lane owns 2 channels (packed uint).
template <int DOUT, bool BNRELU, bool OUT_BF16>
__global__ __launch_bounds__(64) void k_agg(
    const ushort* __restrict__ Zb, const int* __restrict__ row_start,
    const int* __restrict__ csr_src,
    const float* __restrict__ gamma, const float* __restrict__ beta,
    const float* __restrict__ mean, const float* __restrict__ var,
    const float* __restrict__ Yf, void* __restrict__ Hout) {
    constexpr int LG = DOUT / 2;          // lanes per node: 64 or 32
    constexpr int NPB = 64 / LG;          // nodes per block: 1 or 2
    int t = threadIdx.x;
    int sub = t / LG, tt = t % LG;
    int n = blockIdx.x * NPB + sub;
    int s0 = row_start[n], s1 = row_start[n + 1];
    int c2 = tt * 2;
    float a0 = 0.f, a1 = 0.f;
    int e = s0;
    for (; e + 4 <= s1; e += 4) {
        int i0 = csr_src[e], i1 = csr_src[e + 1], i2 = csr_src[e + 2], i3 = csr_src[e + 3];
        uint u0 = *(const uint*)&Zb[(size_t)i0 * DOUT + c2];
        uint u1 = *(const uint*)&Zb[(size_t)i1 * DOUT + c2];
        uint u2 = *(const uint*)&Zb[(size_t)i2 * DOUT + c2];
        uint u3 = *(const uint*)&Zb[(size_t)i3 * DOUT + c2];
        a0 += __uint_as_float(u0 << 16) + __uint_as_float(u1 << 16)
            + __uint_as_float(u2 << 16) + __uint_as_float(u3 << 16);
        a1 += __uint_as_float(u0 & 0xffff0000u) + __uint_as_float(u1 & 0xffff0000u)
            + __uint_as_float(u2 & 0xffff0000u) + __uint_as_float(u3 & 0xffff0000u);
    }
    for (; e < s1; ++e) {
        uint u = *(const uint*)&Zb[(size_t)csr_src[e] * DOUT + c2];
        a0 += __uint_as_float(u << 16);
        a1 += __uint_as_float(u & 0xffff0000u);
    }
    float inv = 1.f / fmaxf((float)(s1 - s0), 1.f);
    size_t base = (size_t)n * DOUT + c2;
    float h0 = Yf[base] + a0 * inv;
    float h1 = Yf[base + 1] + a1 * inv;
    if (BNRELU) {
        float g0 = gamma[c2], g1 = gamma[c2 + 1];
        float m0 = mean[c2], m1 = mean[c2 + 1];
        float v0 = var[c2], v1 = var[c2 + 1];
        float b0 = beta[c2], b1 = beta[c2 + 1];
        h0 = fmaxf((h0 - m0) * (g0 * rsqrtf(v0 + EPS)) + b0, 0.f);
        h1 = fmaxf((h1 - m1) * (g1 * rsqrtf(v1 + EPS)) + b1, 0.f);
    }
    if (OUT_BF16) {
        uint pk = (uint)f2bf(h0) | ((uint)f2bf(h1) << 16);
        *(uint*)&((ushort*)Hout)[base] = pk;
    } else {
        float2 o; o.x = h0; o.y = h1;
        *(float2*)&((float*)Hout)[base] = o;
    }
}

// ---------------- launch ----------------

static inline size_t align256(size_t x) { return (x + 255) & ~(size_t)255; }

extern "C" void kernel_launch(void* const* d_in, const int* in_sizes, int n_in,
                              void* d_out, int out_size, void* d_ws, size_t ws_size,
                              hipStream_t stream) {
    const float* x    = (const float*)d_in[0];
    const int*   ei   = (const int*)d_in[1];      // int32 (JAX default int)
    const float* w_l1 = (const float*)d_in[2];
    const float* b_l1 = (const float*)d_in[3];
    const float* w_r1 = (const float*)d_in[4];
    const float* g1   = (const float*)d_in[5];
    const float* be1  = (const float*)d_in[6];
    const float* m1   = (const float*)d_in[7];
    const float* v1   = (const float*)d_in[8];
    const float* w_l2 = (const float*)d_in[9];
    const float* b_l2 = (const float*)d_in[10];
    const float* w_r2 = (const float*)d_in[11];
    const float* g2   = (const float*)d_in[12];
    const float* be2  = (const float*)d_in[13];
    const float* m2   = (const float*)d_in[14];
    const float* v2   = (const float*)d_in[15];
    const float* w_l3 = (const float*)d_in[16];
    const float* b_l3 = (const float*)d_in[17];
    const float* w_r3 = (const float*)d_in[18];
    float* out = (float*)d_out;

    char* w = (char*)d_ws;
    int* deg       = (int*)w;  w += align256((size_t)N_NODES * 4);
    int* row_start = (int*)w;  w += align256((size_t)(N_NODES + 1) * 4);
    int* cursor    = (int*)w;  w += align256((size_t)N_NODES * 4);
    int* bsum      = (int*)w;  w += align256((size_t)NB_SCAN * 4);
    int* csr_src   = (int*)w;  w += align256((size_t)N_EDGES * 4);
    ushort* hb     = (ushort*)w; w += align256((size_t)N_NODES * D * 2);
    ushort* Zb     = (ushort*)w; w += align256((size_t)N_NODES * D * 2);
    float*  Yf     = (float*)w;  w += align256((size_t)N_NODES * D * 4);
    ushort* w2_1   = (ushort*)w; w += align256((size_t)2 * D * D * 2);
    ushort* w2_2   = (ushort*)w; w += align256((size_t)2 * D * D * 2);
    ushort* w2_3   = (ushort*)w; w += align256((size_t)D * D * 2);

    hipMemsetAsync(deg, 0, (size_t)N_NODES * 4, stream);

    int eb = (N_EDGES + 255) / 256;
    k_hist<<<eb, 256, 0, stream>>>(ei, deg);
    k_scan1<<<NB_SCAN, 256, 0, stream>>>(deg, bsum);
    k_scan2<<<1, 1, 0, stream>>>(bsum, row_start);
    k_scan3<<<NB_SCAN, 256, 0, stream>>>(deg, bsum, row_start, cursor);
    k_fill<<<eb, 256, 0, stream>>>(ei, cursor, csr_src);

    // casts
    int n4 = N_NODES * D / 4;
    k_cast_x<<<(n4 + 255) / 256, 256, 0, stream>>>(x, hb, n4);
    k_cast_w<<<(2 * D * D + 255) / 256, 256, 0, stream>>>(w_l1, w_r1, w2_1, D);
    k_cast_w<<<(2 * D * D + 255) / 256, 256, 0, stream>>>(w_l2, w_r2, w2_2, D);
    k_cast_w<<<(D * D + 255) / 256, 256, 0, stream>>>(w_l3, w_r3, w2_3, 64);

    int gb = (N_NODES + 63) / 64;   // 1563

    // layer 1
    k_gemm_mfma<128><<<gb, 256, 0, stream>>>(hb, w2_1, b_l1, Zb, Yf);
    k_agg<128, true, true><<<N_NODES, 64, 0, stream>>>(Zb, row_start, csr_src, g1, be1, m1, v1, Yf, hb);
    // layer 2
    k_gemm_mfma<128><<<gb, 256, 0, stream>>>(hb, w2_2, b_l2, Zb, Yf);
    k_agg<128, true, true><<<N_NODES, 64, 0, stream>>>(Zb, row_start, csr_src, g2, be2, m2, v2, Yf, hb);
    // layer 3
    k_gemm_mfma<64><<<gb, 256, 0, stream>>>(hb, w2_3, b_l3, Zb, Yf);
    k_agg<64, false, false><<<N_NODES / 2, 64, 0, stream>>>(Zb, row_start, csr_src, b_l3, b_l3, b_l3, b_l3, Yf, out);
}